// Round 2
// baseline (319.826 us; speedup 1.0000x reference)
//
#include <hip/hip_runtime.h>

// SNN: B=4096 batches, T=784 timesteps, H=128 hidden, OUT=10.
// Mapping: 1 wave (64 thr) per block; 4 batches/wave; 16 lanes/batch; 8 h/lane.
// Per step: LIF1 + per-lane partial dot (s1 * W2) -> LDS transpose (pad 13)
// -> 40 lanes (batch,out) reduce 16 partials, LIF2, spike count.
// Single-wave block: DS ops are in-order per wave; no __syncthreads needed
// (avoids per-step vmcnt(0) drain that would break the x float4 prefetch).

#define T_STEPS 784
#define T4      196
#define HID     128
#define NOUT    10
#define TSTART  522   // T*2//3

__global__ __launch_bounds__(64, 1)
void snn_kernel(const float* __restrict__ x,    // [B, T]
                const float* __restrict__ W1,   // [H] (H x 1)
                const float* __restrict__ b1,   // [H]
                const float* __restrict__ W2,   // [OUT, H]
                const float* __restrict__ b2,   // [OUT]
                float* __restrict__ out)        // [B, OUT]
{
    __shared__ float lds[64 * 13];              // 13-pad: 2-way bank alias only (free)

    const int tid  = threadIdx.x;
    const int g    = tid >> 4;                  // batch group 0..3
    const int l16  = tid & 15;
    const int batch = blockIdx.x * 4 + g;
    const int h0   = l16 * 8;

    // ---- hoist weights into registers ----
    float w1v[8], b1v[8], w2v[NOUT][8];
#pragma unroll
    for (int j = 0; j < 8; ++j) { w1v[j] = W1[h0 + j]; b1v[j] = b1[h0 + j]; }
#pragma unroll
    for (int o = 0; o < NOUT; ++o)
#pragma unroll
        for (int j = 0; j < 8; ++j) w2v[o][j] = W2[o * HID + h0 + j];

    float v1[8];
#pragma unroll
    for (int j = 0; j < 8; ++j) v1[j] = 0.0f;

    // ---- B-phase (reduction) lane setup: lane = bb*10 + ob, lanes 0..39 ----
    const bool bact = (tid < 40);
    const int  bb   = tid / 10;
    const int  ob   = tid - bb * 10;
    float b2v = 0.0f;
    if (bact) b2v = b2[ob];
    float v2 = 0.0f, outacc = 0.0f;

    const float4* xrow = reinterpret_cast<const float4*>(x + (size_t)batch * T_STEPS);
    float4 xc = xrow[0];

    for (int t4 = 0; t4 < T4; ++t4) {
        float4 xn = xrow[(t4 + 1 < T4) ? (t4 + 1) : t4];   // prefetch next 4 steps
        const float xs[4] = {xc.x, xc.y, xc.z, xc.w};

#pragma unroll
        for (int u = 0; u < 4; ++u) {
            const float xv = xs[u];
            float acc[NOUT];

            // ---- phase A: LIF1 + partial dot over this lane's 8 h ----
            {   // j = 0 initializes acc with a mul (saves 10 movs)
                float h1 = fmaf(xv, w1v[0], b1v[0]);
                float d  = h1 - v1[0];
                float vn = fmaf(d, 0.5f, v1[0]);
                bool  s  = (vn >= 1.0f);
                float sf = s ? 1.0f : 0.0f;
                v1[0]    = s ? 0.0f : vn;
#pragma unroll
                for (int o = 0; o < NOUT; ++o) acc[o] = sf * w2v[o][0];
            }
#pragma unroll
            for (int j = 1; j < 8; ++j) {
                float h1 = fmaf(xv, w1v[j], b1v[j]);
                float d  = h1 - v1[j];
                float vn = fmaf(d, 0.5f, v1[j]);
                bool  s  = (vn >= 1.0f);
                float sf = s ? 1.0f : 0.0f;
                v1[j]    = s ? 0.0f : vn;
#pragma unroll
                for (int o = 0; o < NOUT; ++o) acc[o] = fmaf(sf, w2v[o][j], acc[o]);
            }

            // ---- write partials (bank-friendly: stride 13 floats) ----
#pragma unroll
            for (int o = 0; o < NOUT; ++o) lds[tid * 13 + o] = acc[o];

            // ---- phase B: 40 lanes each own one (batch, out) ----
            if (bact) {
                float p[16];
#pragma unroll
                for (int k = 0; k < 16; ++k) p[k] = lds[(bb * 16 + k) * 13 + ob];
                float s0 = ((p[0] + p[1]) + (p[2] + p[3])) + ((p[4] + p[5]) + (p[6] + p[7]));
                float s1 = ((p[8] + p[9]) + (p[10] + p[11])) + ((p[12] + p[13]) + (p[14] + p[15]));
                float h2 = (s0 + s1) + b2v;
                float d2  = h2 - v2;
                float v2n = fmaf(d2, 0.5f, v2);
                bool  sp  = (v2n >= 1.0f);
                v2 = sp ? 0.0f : v2n;
                const int t = t4 * 4 + u;
                outacc += (sp && (t >= TSTART)) ? 1.0f : 0.0f;
            }
        }
        xc = xn;
    }

    if (bact) out[blockIdx.x * 40 + tid] = outacc;   // = out[(blk*4+bb)*10 + ob]
}

extern "C" void kernel_launch(void* const* d_in, const int* in_sizes, int n_in,
                              void* d_out, int out_size, void* d_ws, size_t ws_size,
                              hipStream_t stream)
{
    const float* x  = (const float*)d_in[0];
    const float* W1 = (const float*)d_in[1];
    const float* b1 = (const float*)d_in[2];
    const float* W2 = (const float*)d_in[3];
    const float* b2 = (const float*)d_in[4];
    float* out = (float*)d_out;

    // 4096 batches / 4 per block = 1024 blocks of 64 threads (1 wave each)
    snn_kernel<<<dim3(1024), dim3(64), 0, stream>>>(x, W1, b1, W2, b2, out);
}